// Round 1
// baseline (208.814 us; speedup 1.0000x reference)
//
#include <hip/hip_runtime.h>

#define KAN_GRID_SIZE 13
#define KAN_SPLINE_ORDER 3
#define NB (KAN_GRID_SIZE + KAN_SPLINE_ORDER)            // 16 basis functions
#define NPTS (KAN_GRID_SIZE + 2 * KAN_SPLINE_ORDER + 1)  // 20 knots
#define N_IN 4096
#define N_OUT 4096
#define ROW_F4 (N_IN * NB / 4)                            // 16384 float4 per output row

// Kernel 1: B[i,k] = order-3 B-spline basis of tanh(inputs[i]).
// Cox-de Boor recursion, fully unrolled, all in registers. Knot values and
// denominators computed exactly as the JAX reference (f32 grid differences).
__global__ void basis_kernel(const float* __restrict__ inputs,
                             float* __restrict__ Bout) {
    int i = blockIdx.x * blockDim.x + threadIdx.x;
    if (i >= N_IN) return;
    const float H = 2.0f / 13.0f;
    float x = tanhf(inputs[i]);

    float g[NPTS];
#pragma unroll
    for (int j = 0; j < NPTS; ++j)
        g[j] = (float)(j - KAN_SPLINE_ORDER) * H - 1.0f;

    float Bv[NPTS - 1];  // 19 degree-0 indicators
#pragma unroll
    for (int j = 0; j < NPTS - 1; ++j)
        Bv[j] = (x >= g[j] && x < g[j + 1]) ? 1.0f : 0.0f;

#pragma unroll
    for (int d = 1; d <= KAN_SPLINE_ORDER; ++d) {
#pragma unroll
        for (int j = 0; j + d < NPTS - 1; ++j) {
            float left  = (x - g[j]) / (g[j + d] - g[j]) * Bv[j];
            float right = (g[j + d + 1] - x) / (g[j + d + 1] - g[j + 1]) * Bv[j + 1];
            Bv[j] = left + right;  // in-place ok: Bv[j+1] still old value
        }
    }

#pragma unroll
    for (int k = 0; k < NB; ++k)
        Bout[i * NB + k] = Bv[k];
}

// Kernel 2: out[row] = dot(W[row,:,:], B) + bias[row].
// One 256-thread block per row; float4 coalesced W stream (HBM-bound),
// B (256 KiB) comes from L2.
__global__ __launch_bounds__(256) void gemv_kernel(const float* __restrict__ W,
                                                   const float* __restrict__ B,
                                                   const float* __restrict__ bias,
                                                   float* __restrict__ out) {
    const int row = blockIdx.x;
    const float4* __restrict__ Wr = (const float4*)W + (size_t)row * ROW_F4;
    const float4* __restrict__ Bv = (const float4*)B;

    float acc = 0.0f;
    for (int idx = threadIdx.x; idx < ROW_F4; idx += 256) {
        float4 w = Wr[idx];
        float4 b = Bv[idx];
        acc = fmaf(w.x, b.x, acc);
        acc = fmaf(w.y, b.y, acc);
        acc = fmaf(w.z, b.z, acc);
        acc = fmaf(w.w, b.w, acc);
    }

    // wave-64 butterfly reduce
#pragma unroll
    for (int off = 32; off >= 1; off >>= 1)
        acc += __shfl_xor(acc, off);

    __shared__ float s[4];
    int wave = threadIdx.x >> 6;
    if ((threadIdx.x & 63) == 0) s[wave] = acc;
    __syncthreads();
    if (threadIdx.x == 0)
        out[row] = s[0] + s[1] + s[2] + s[3] + bias[row];
}

extern "C" void kernel_launch(void* const* d_in, const int* in_sizes, int n_in,
                              void* d_out, int out_size, void* d_ws, size_t ws_size,
                              hipStream_t stream) {
    const float* inputs = (const float*)d_in[0];
    const float* W      = (const float*)d_in[1];
    const float* bias   = (const float*)d_in[2];
    float* out = (float*)d_out;
    float* Bws = (float*)d_ws;  // 4096*16 f32 = 256 KiB scratch

    basis_kernel<<<N_IN / 256, 256, 0, stream>>>(inputs, Bws);
    gemv_kernel<<<N_OUT, 256, 0, stream>>>(W, Bws, bias, out);
}

// Round 3
// 181.056 us; speedup vs baseline: 1.1533x; 1.1533x over previous
//
#include <hip/hip_runtime.h>

#define KAN_GRID_SIZE 13
#define KAN_SPLINE_ORDER 3
#define NB (KAN_GRID_SIZE + KAN_SPLINE_ORDER)            // 16 basis functions
#define NPTS (KAN_GRID_SIZE + 2 * KAN_SPLINE_ORDER + 1)  // 20 knots
#define N_IN 4096
#define N_OUT 4096
#define ROW_F4 (N_IN * NB / 4)                            // 16384 float4 per output row

typedef float f32x4 __attribute__((ext_vector_type(4)));  // native vec: ok for nontemporal builtin

// Kernel 1: B[i,k] = order-3 B-spline basis of tanh(inputs[i]).
// Cox-de Boor recursion, fully unrolled, registers only. Knots/denominators
// computed exactly as the JAX reference (f32 grid arithmetic).
__global__ void basis_kernel(const float* __restrict__ inputs,
                             float* __restrict__ Bout) {
    int i = blockIdx.x * blockDim.x + threadIdx.x;
    if (i >= N_IN) return;
    const float H = 2.0f / 13.0f;
    float x = tanhf(inputs[i]);

    float g[NPTS];
#pragma unroll
    for (int j = 0; j < NPTS; ++j)
        g[j] = (float)(j - KAN_SPLINE_ORDER) * H - 1.0f;

    float Bv[NPTS - 1];
#pragma unroll
    for (int j = 0; j < NPTS - 1; ++j)
        Bv[j] = (x >= g[j] && x < g[j + 1]) ? 1.0f : 0.0f;

#pragma unroll
    for (int d = 1; d <= KAN_SPLINE_ORDER; ++d) {
#pragma unroll
        for (int j = 0; j + d < NPTS - 1; ++j) {
            float left  = (x - g[j]) / (g[j + d] - g[j]) * Bv[j];
            float right = (g[j + d + 1] - x) / (g[j + d + 1] - g[j + 1]) * Bv[j + 1];
            Bv[j] = left + right;
        }
    }

#pragma unroll
    for (int k = 0; k < NB; ++k)
        Bout[i * NB + k] = Bv[k];
}

// Kernel 2: out[row] = dot(W[row,:,:], B) + bias[row].
// One 256-thread block per row. W is a pure 1 GiB HBM stream -> nontemporal
// (nt) loads so it doesn't evict the shared 256 KiB B table from L2.
// Unroll x2 with two accumulators: 4 independent loads in flight per thread
// per iteration, two independent FMA chains.
__global__ __launch_bounds__(256) void gemv_kernel(const float* __restrict__ W,
                                                   const float* __restrict__ B,
                                                   const float* __restrict__ bias,
                                                   float* __restrict__ out) {
    const int row = blockIdx.x;
    const f32x4* __restrict__ Wr = (const f32x4*)W + (size_t)row * ROW_F4;
    const f32x4* __restrict__ Bv = (const f32x4*)B;

    float acc0 = 0.0f, acc1 = 0.0f;
#pragma unroll 4
    for (int it = 0; it < ROW_F4 / 512; ++it) {
        int base = it * 512 + threadIdx.x;
        // unit-stride coalesced within each instruction; W marked nontemporal
        f32x4 w0 = __builtin_nontemporal_load(&Wr[base]);
        f32x4 w1 = __builtin_nontemporal_load(&Wr[base + 256]);
        f32x4 b0 = Bv[base];
        f32x4 b1 = Bv[base + 256];
        acc0 = fmaf(w0.x, b0.x, acc0);
        acc0 = fmaf(w0.y, b0.y, acc0);
        acc0 = fmaf(w0.z, b0.z, acc0);
        acc0 = fmaf(w0.w, b0.w, acc0);
        acc1 = fmaf(w1.x, b1.x, acc1);
        acc1 = fmaf(w1.y, b1.y, acc1);
        acc1 = fmaf(w1.z, b1.z, acc1);
        acc1 = fmaf(w1.w, b1.w, acc1);
    }
    float acc = acc0 + acc1;

    // wave-64 butterfly reduce
#pragma unroll
    for (int off = 32; off >= 1; off >>= 1)
        acc += __shfl_xor(acc, off);

    __shared__ float s[4];
    int wave = threadIdx.x >> 6;
    if ((threadIdx.x & 63) == 0) s[wave] = acc;
    __syncthreads();
    if (threadIdx.x == 0)
        out[row] = s[0] + s[1] + s[2] + s[3] + bias[row];
}

extern "C" void kernel_launch(void* const* d_in, const int* in_sizes, int n_in,
                              void* d_out, int out_size, void* d_ws, size_t ws_size,
                              hipStream_t stream) {
    const float* inputs = (const float*)d_in[0];
    const float* W      = (const float*)d_in[1];
    const float* bias   = (const float*)d_in[2];
    float* out = (float*)d_out;
    float* Bws = (float*)d_ws;  // 4096*16 f32 = 256 KiB scratch

    basis_kernel<<<N_IN / 256, 256, 0, stream>>>(inputs, Bws);
    gemv_kernel<<<N_OUT, 256, 0, stream>>>(W, Bws, bias, out);
}

// Round 4
// 166.087 us; speedup vs baseline: 1.2573x; 1.0901x over previous
//
#include <hip/hip_runtime.h>

#define KAN_GRID_SIZE 13
#define KAN_SPLINE_ORDER 3
#define NB (KAN_GRID_SIZE + KAN_SPLINE_ORDER)            // 16 basis functions
#define NPTS (KAN_GRID_SIZE + 2 * KAN_SPLINE_ORDER + 1)  // 20 knots
#define N_IN 4096
#define N_OUT 4096
#define ROW_F4 (N_IN * NB / 4)                            // 16384 float4 per output row
#define ROWS_PER_BLOCK 2

typedef float f32x4 __attribute__((ext_vector_type(4)));

// Kernel 1: B[i,k] = order-3 B-spline basis of tanh(inputs[i]).
// Cox-de Boor recursion, fully unrolled, registers only. Knots/denominators
// computed exactly as the JAX reference (f32 grid arithmetic).
__global__ void basis_kernel(const float* __restrict__ inputs,
                             float* __restrict__ Bout) {
    int i = blockIdx.x * blockDim.x + threadIdx.x;
    if (i >= N_IN) return;
    const float H = 2.0f / 13.0f;
    float x = tanhf(inputs[i]);

    float g[NPTS];
#pragma unroll
    for (int j = 0; j < NPTS; ++j)
        g[j] = (float)(j - KAN_SPLINE_ORDER) * H - 1.0f;

    float Bv[NPTS - 1];
#pragma unroll
    for (int j = 0; j < NPTS - 1; ++j)
        Bv[j] = (x >= g[j] && x < g[j + 1]) ? 1.0f : 0.0f;

#pragma unroll
    for (int d = 1; d <= KAN_SPLINE_ORDER; ++d) {
#pragma unroll
        for (int j = 0; j + d < NPTS - 1; ++j) {
            float left  = (x - g[j]) / (g[j + d] - g[j]) * Bv[j];
            float right = (g[j + d + 1] - x) / (g[j + d + 1] - g[j + 1]) * Bv[j + 1];
            Bv[j] = left + right;
        }
    }

#pragma unroll
    for (int k = 0; k < NB; ++k)
        Bout[i * NB + k] = Bv[k];
}

// Kernel 2: out[r0..r0+1] = dot(W[r,:,:], B) + bias[r].
// 2 rows per block: one shared B stream feeds both rows' FMA chains,
// halving B VMEM instructions per W byte. W rows for a block are contiguous
// (512 KiB window) -> good DRAM page locality. W loads nontemporal so the
// streamed 1 GiB doesn't evict the 256 KiB B table from L2.
__global__ __launch_bounds__(256) void gemv_kernel(const float* __restrict__ W,
                                                   const float* __restrict__ B,
                                                   const float* __restrict__ bias,
                                                   float* __restrict__ out) {
    const int r0 = blockIdx.x * ROWS_PER_BLOCK;
    const f32x4* __restrict__ W0 = (const f32x4*)W + (size_t)r0 * ROW_F4;
    const f32x4* __restrict__ W1 = W0 + ROW_F4;
    const f32x4* __restrict__ Bv = (const f32x4*)B;

    float a00 = 0.0f, a01 = 0.0f, a10 = 0.0f, a11 = 0.0f;
#pragma unroll 4
    for (int it = 0; it < ROW_F4 / 512; ++it) {
        int base = it * 512 + threadIdx.x;
        f32x4 b0  = Bv[base];
        f32x4 b1  = Bv[base + 256];
        f32x4 w00 = __builtin_nontemporal_load(&W0[base]);
        f32x4 w01 = __builtin_nontemporal_load(&W0[base + 256]);
        f32x4 w10 = __builtin_nontemporal_load(&W1[base]);
        f32x4 w11 = __builtin_nontemporal_load(&W1[base + 256]);
        a00 = fmaf(w00.x, b0.x, a00); a00 = fmaf(w00.y, b0.y, a00);
        a00 = fmaf(w00.z, b0.z, a00); a00 = fmaf(w00.w, b0.w, a00);
        a01 = fmaf(w01.x, b1.x, a01); a01 = fmaf(w01.y, b1.y, a01);
        a01 = fmaf(w01.z, b1.z, a01); a01 = fmaf(w01.w, b1.w, a01);
        a10 = fmaf(w10.x, b0.x, a10); a10 = fmaf(w10.y, b0.y, a10);
        a10 = fmaf(w10.z, b0.z, a10); a10 = fmaf(w10.w, b0.w, a10);
        a11 = fmaf(w11.x, b1.x, a11); a11 = fmaf(w11.y, b1.y, a11);
        a11 = fmaf(w11.z, b1.z, a11); a11 = fmaf(w11.w, b1.w, a11);
    }
    float accA = a00 + a01;  // row r0
    float accB = a10 + a11;  // row r0+1

    // wave-64 butterfly reduce, both rows
#pragma unroll
    for (int off = 32; off >= 1; off >>= 1) {
        accA += __shfl_xor(accA, off);
        accB += __shfl_xor(accB, off);
    }

    __shared__ float s[4][ROWS_PER_BLOCK];
    int wave = threadIdx.x >> 6;
    if ((threadIdx.x & 63) == 0) { s[wave][0] = accA; s[wave][1] = accB; }
    __syncthreads();
    if (threadIdx.x < ROWS_PER_BLOCK) {
        int r = r0 + threadIdx.x;
        out[r] = s[0][threadIdx.x] + s[1][threadIdx.x] +
                 s[2][threadIdx.x] + s[3][threadIdx.x] + bias[r];
    }
}

extern "C" void kernel_launch(void* const* d_in, const int* in_sizes, int n_in,
                              void* d_out, int out_size, void* d_ws, size_t ws_size,
                              hipStream_t stream) {
    const float* inputs = (const float*)d_in[0];
    const float* W      = (const float*)d_in[1];
    const float* bias   = (const float*)d_in[2];
    float* out = (float*)d_out;
    float* Bws = (float*)d_ws;  // 4096*16 f32 = 256 KiB scratch

    basis_kernel<<<N_IN / 256, 256, 0, stream>>>(inputs, Bws);
    gemv_kernel<<<N_OUT / ROWS_PER_BLOCK, 256, 0, stream>>>(W, Bws, bias, out);
}